// Round 2
// baseline (172.990 us; speedup 1.0000x reference)
//
#include <hip/hip_runtime.h>

#define D_TOT 10000
#define ROWB  40000            // bytes per table row (D_TOT*4)
#define NLEV  256
#define NPIX  131072           // 32*64*64
#define DPAD  10048            // padded D for partials (covers chunk 156 full stores)
#define NCHUNK 157             // ceil(10000/64)

__device__ __forceinline__ float4 fma4(const float4 a, const float4 b, const float4 c) {
  float4 r;
  r.x = fmaf(a.x, b.x, c.x);
  r.y = fmaf(a.y, b.y, c.y);
  r.z = fmaf(a.z, b.z, c.z);
  r.w = fmaf(a.w, b.w, c.w);
  return r;
}

// image levels (int32) -> pre-shifted LDS byte offsets (level * 256B)
__global__ void prep_kernel(const int* __restrict__ img, int* __restrict__ idxoff) {
  int p = blockIdx.x * 256 + threadIdx.x;
  if (p < NPIX) idxoff[p] = img[p] << 8;
}

// Each block: one 64-d chunk x one ROWS-row strip, all 32 images.
// 512 threads = 16 d-subgroups (4 d each, float4) x 32 image slots.
// 64 KB LDS -> 2 blocks/CU -> 16 waves/CU (was 8 with 256-thr blocks).
template<int ROWS>
__global__ __launch_bounds__(512, 4)
void encode_kernel(const float* __restrict__ V, const float* __restrict__ X,
                   const float* __restrict__ Y, const int* __restrict__ idxoff,
                   float* __restrict__ part) {
  __shared__ float4 vlds[NLEV * 16];   // 64 KB: [level][16 x float4 = 64 d]
  const int tid   = threadIdx.x;
  const int chunk = blockIdx.x;
  const int q     = blockIdx.y;

  // ---- stage V tile: rows = levels, cols = this block's 64 d's ----
  {
    const int seg = tid & 15;          // 16B segment within the 256B level row
    const int l0  = tid >> 4;          // 0..31
    int off = chunk * 256 + seg * 16;  // byte offset into a V row
    if (off + 16 > ROWB) off = ROWB - 16;   // clamp for partial last chunk (values unused)
    const char* Vb = (const char*)V;
#pragma unroll
    for (int k = 0; k < 8; ++k) {
      const int l = k * 32 + l0;
      vlds[l * 16 + seg] = *(const float4*)(Vb + (size_t)l * ROWB + off);
    }
  }
  __syncthreads();

  const int dsub = tid & 15;
  const int b    = tid >> 4;           // image slot 0..31
  const char* vbase = (const char*)vlds + dsub * 16;
  const int d4  = chunk * 64 + dsub * 4;
  const int d4c = d4 > (D_TOT - 4) ? (D_TOT - 4) : d4;   // clamped for x/y loads (lanes past D discarded)
  const int ybase = q * ROWS;

  float4 rowacc[ROWS];
#pragma unroll
  for (int y = 0; y < ROWS; ++y) rowacc[y] = make_float4(0.f, 0.f, 0.f, 0.f);
  const int* iptr = idxoff + b * 4096 + ybase * 64;

#pragma unroll 1
  for (int wt = 0; wt < 8; ++wt) {
    // hoist x fragments for this 8-wide w tile (registers, reused over ROWS rows)
    float4 xt[8];
#pragma unroll
    for (int w = 0; w < 8; ++w)
      xt[w] = *(const float4*)(X + (size_t)(wt * 8 + w) * D_TOT + d4c);
#pragma unroll
    for (int y = 0; y < ROWS; ++y) {
      const int* ip = iptr + y * 64 + wt * 8;
      const int4 o0 = *(const int4*)ip;
      const int4 o1 = *(const int4*)(ip + 4);
      float4 v;
      v = *(const float4*)(vbase + o0.x); rowacc[y] = fma4(xt[0], v, rowacc[y]);
      v = *(const float4*)(vbase + o0.y); rowacc[y] = fma4(xt[1], v, rowacc[y]);
      v = *(const float4*)(vbase + o0.z); rowacc[y] = fma4(xt[2], v, rowacc[y]);
      v = *(const float4*)(vbase + o0.w); rowacc[y] = fma4(xt[3], v, rowacc[y]);
      v = *(const float4*)(vbase + o1.x); rowacc[y] = fma4(xt[4], v, rowacc[y]);
      v = *(const float4*)(vbase + o1.y); rowacc[y] = fma4(xt[5], v, rowacc[y]);
      v = *(const float4*)(vbase + o1.z); rowacc[y] = fma4(xt[6], v, rowacc[y]);
      v = *(const float4*)(vbase + o1.w); rowacc[y] = fma4(xt[7], v, rowacc[y]);
    }
  }

  // apply y binding in ascending row order, then store partial for this strip
  float4 acc = make_float4(0.f, 0.f, 0.f, 0.f);
#pragma unroll
  for (int y = 0; y < ROWS; ++y) {
    const float4 yv = *(const float4*)(Y + (size_t)(ybase + y) * D_TOT + d4c);
    acc = fma4(yv, rowacc[y], acc);
  }
  *(float4*)(part + (size_t)(q * 32 + b) * DPAD + d4) = acc;
}

__global__ void finalize_kernel(const float* __restrict__ part, float* __restrict__ out, int R) {
  const int d = blockIdx.x * 256 + threadIdx.x;
  const int b = blockIdx.y;
  if (d >= D_TOT) return;
  float s = 0.f;
  for (int r = 0; r < R; ++r) s += part[(size_t)(r * 32 + b) * DPAD + d];
  out[(size_t)b * D_TOT + d] = s > 0.f ? 1.0f : -1.0f;
}

extern "C" void kernel_launch(void* const* d_in, const int* in_sizes, int n_in,
                              void* d_out, int out_size, void* d_ws, size_t ws_size,
                              hipStream_t stream) {
  const float* V = (const float*)d_in[0];   // [256][10000]
  const float* X = (const float*)d_in[1];   // [64][10000]
  const float* Y = (const float*)d_in[2];   // [64][10000]
  const int*  img = (const int*)d_in[3];    // [32][1][64][64] levels
  float* out = (float*)d_out;               // [32][10000]

  int* idxoff = (int*)d_ws;
  const size_t base = 524288;               // 131072 * 4
  float* part = (float*)((char*)d_ws + base);

  int R;
  if      (ws_size >= base + (size_t)8 * 32 * DPAD * 4) R = 8;
  else if (ws_size >= base + (size_t)4 * 32 * DPAD * 4) R = 4;
  else                                                  R = 2;

  prep_kernel<<<dim3(512), dim3(256), 0, stream>>>(img, idxoff);
  if (R == 8)
    encode_kernel<8><<<dim3(NCHUNK, 8), dim3(512), 0, stream>>>(V, X, Y, idxoff, part);
  else if (R == 4)
    encode_kernel<16><<<dim3(NCHUNK, 4), dim3(512), 0, stream>>>(V, X, Y, idxoff, part);
  else
    encode_kernel<32><<<dim3(NCHUNK, 2), dim3(512), 0, stream>>>(V, X, Y, idxoff, part);
  finalize_kernel<<<dim3(40, 32), dim3(256), 0, stream>>>(part, out, R);
}

// Round 3
// 141.925 us; speedup vs baseline: 1.2189x; 1.2189x over previous
//
#include <hip/hip_runtime.h>

#define D_TOT 10000
#define ROWB  40000            // bytes per table row (D_TOT*4)
#define NLEV  256
#define NPIX  131072           // 32*64*64
#define DPAD  10048            // padded D for partials (covers chunk 156 full stores)
#define NCHUNK 157             // ceil(10000/64)

__device__ __forceinline__ float4 fma4(const float4 a, const float4 b, const float4 c) {
  float4 r;
  r.x = fmaf(a.x, b.x, c.x);
  r.y = fmaf(a.y, b.y, c.y);
  r.z = fmaf(a.z, b.z, c.z);
  r.w = fmaf(a.w, b.w, c.w);
  return r;
}

// image levels (int32) -> pre-shifted LDS byte offsets (level * 256B)
__global__ void prep_kernel(const int* __restrict__ img, int* __restrict__ idxoff) {
  int p = blockIdx.x * 256 + threadIdx.x;
  if (p < NPIX) idxoff[p] = img[p] << 8;
}

// Each block: one 64-d chunk x one ROWS-row strip, all 32 images.
// 512 threads = 16 d-subgroups (4 d each, float4) x 32 image slots.
// launch_bounds(512,2): under CUDA semantics (2 blocks/CU min) -> 16 waves/CU
// -> VGPR cap 128 (round-2's (512,4) was read as 4 blocks/CU -> cap 64 -> spill).
template<int ROWS>
__global__ __launch_bounds__(512, 2)
void encode_kernel(const float* __restrict__ V, const float* __restrict__ X,
                   const float* __restrict__ Y, const int* __restrict__ idxoff,
                   float* __restrict__ part) {
  __shared__ float4 vlds[NLEV * 16];   // 64 KB: [level][16 x float4 = 64 d]
  const int tid   = threadIdx.x;
  const int chunk = blockIdx.x;
  const int q     = blockIdx.y;

  // ---- stage V tile: rows = levels, cols = this block's 64 d's ----
  {
    const int seg = tid & 15;          // 16B segment within the 256B level row
    const int l0  = tid >> 4;          // 0..31
    int off = chunk * 256 + seg * 16;  // byte offset into a V row
    if (off + 16 > ROWB) off = ROWB - 16;   // clamp for partial last chunk (values unused)
    const char* Vb = (const char*)V;
#pragma unroll
    for (int k = 0; k < 8; ++k) {
      const int l = k * 32 + l0;
      vlds[l * 16 + seg] = *(const float4*)(Vb + (size_t)l * ROWB + off);
    }
  }
  __syncthreads();

  const int dsub = tid & 15;
  const int b    = tid >> 4;           // image slot 0..31
  const char* vbase = (const char*)vlds + dsub * 16;
  const int d4  = chunk * 64 + dsub * 4;
  const int d4c = d4 > (D_TOT - 4) ? (D_TOT - 4) : d4;   // clamped for x/y loads (lanes past D discarded)
  const int ybase = q * ROWS;

  float4 rowacc[ROWS];
#pragma unroll
  for (int y = 0; y < ROWS; ++y) rowacc[y] = make_float4(0.f, 0.f, 0.f, 0.f);
  const int* iptr = idxoff + b * 4096 + ybase * 64;

#pragma unroll 1
  for (int wt = 0; wt < 8; ++wt) {
    // hoist x fragments for this 8-wide w tile (registers, reused over ROWS rows)
    float4 xt[8];
#pragma unroll
    for (int w = 0; w < 8; ++w)
      xt[w] = *(const float4*)(X + (size_t)(wt * 8 + w) * D_TOT + d4c);
#pragma unroll
    for (int y = 0; y < ROWS; ++y) {
      const int* ip = iptr + y * 64 + wt * 8;
      const int4 o0 = *(const int4*)ip;
      const int4 o1 = *(const int4*)(ip + 4);
      float4 v;
      v = *(const float4*)(vbase + o0.x); rowacc[y] = fma4(xt[0], v, rowacc[y]);
      v = *(const float4*)(vbase + o0.y); rowacc[y] = fma4(xt[1], v, rowacc[y]);
      v = *(const float4*)(vbase + o0.z); rowacc[y] = fma4(xt[2], v, rowacc[y]);
      v = *(const float4*)(vbase + o0.w); rowacc[y] = fma4(xt[3], v, rowacc[y]);
      v = *(const float4*)(vbase + o1.x); rowacc[y] = fma4(xt[4], v, rowacc[y]);
      v = *(const float4*)(vbase + o1.y); rowacc[y] = fma4(xt[5], v, rowacc[y]);
      v = *(const float4*)(vbase + o1.z); rowacc[y] = fma4(xt[6], v, rowacc[y]);
      v = *(const float4*)(vbase + o1.w); rowacc[y] = fma4(xt[7], v, rowacc[y]);
    }
  }

  // apply y binding in ascending row order, then store partial for this strip
  float4 acc = make_float4(0.f, 0.f, 0.f, 0.f);
#pragma unroll
  for (int y = 0; y < ROWS; ++y) {
    const float4 yv = *(const float4*)(Y + (size_t)(ybase + y) * D_TOT + d4c);
    acc = fma4(yv, rowacc[y], acc);
  }
  *(float4*)(part + (size_t)(q * 32 + b) * DPAD + d4) = acc;
}

__global__ void finalize_kernel(const float* __restrict__ part, float* __restrict__ out, int R) {
  const int d = blockIdx.x * 256 + threadIdx.x;
  const int b = blockIdx.y;
  if (d >= D_TOT) return;
  float s = 0.f;
  for (int r = 0; r < R; ++r) s += part[(size_t)(r * 32 + b) * DPAD + d];
  out[(size_t)b * D_TOT + d] = s > 0.f ? 1.0f : -1.0f;
}

extern "C" void kernel_launch(void* const* d_in, const int* in_sizes, int n_in,
                              void* d_out, int out_size, void* d_ws, size_t ws_size,
                              hipStream_t stream) {
  const float* V = (const float*)d_in[0];   // [256][10000]
  const float* X = (const float*)d_in[1];   // [64][10000]
  const float* Y = (const float*)d_in[2];   // [64][10000]
  const int*  img = (const int*)d_in[3];    // [32][1][64][64] levels
  float* out = (float*)d_out;               // [32][10000]

  int* idxoff = (int*)d_ws;
  const size_t base = 524288;               // 131072 * 4
  float* part = (float*)((char*)d_ws + base);

  const size_t per_strip = (size_t)32 * DPAD * 4;
  int R;
  if      (ws_size >= base + 16 * per_strip) R = 16;
  else if (ws_size >= base +  8 * per_strip) R = 8;
  else                                       R = 4;

  prep_kernel<<<dim3(512), dim3(256), 0, stream>>>(img, idxoff);
  if (R == 16)
    encode_kernel<4><<<dim3(NCHUNK, 16), dim3(512), 0, stream>>>(V, X, Y, idxoff, part);
  else if (R == 8)
    encode_kernel<8><<<dim3(NCHUNK, 8), dim3(512), 0, stream>>>(V, X, Y, idxoff, part);
  else
    encode_kernel<16><<<dim3(NCHUNK, 4), dim3(512), 0, stream>>>(V, X, Y, idxoff, part);
  finalize_kernel<<<dim3(40, 32), dim3(256), 0, stream>>>(part, out, R);
}

// Round 4
// 105.560 us; speedup vs baseline: 1.6388x; 1.3445x over previous
//
#include <hip/hip_runtime.h>

#define D_TOT 10000
#define ROWB  40000            // bytes per V table row (D_TOT*4)
#define NLEV  256
#define NPIX  131072           // 32*64*64
#define DPAD  10016            // padded D for partials (313*32)
#define NCHUNK 313             // ceil(10000/32) 32-d chunks
#define TROW  128              // bytes per level row in LDS tile (32 d * 4B)

__device__ __forceinline__ float4 fma4(const float4 a, const float4 b, const float4 c) {
  float4 r;
  r.x = fmaf(a.x, b.x, c.x);
  r.y = fmaf(a.y, b.y, c.y);
  r.z = fmaf(a.z, b.z, c.z);
  r.w = fmaf(a.w, b.w, c.w);
  return r;
}

// image levels (int32) -> pre-shifted LDS byte offsets (level * 128B tile row)
__global__ void prep_kernel(const int* __restrict__ img, int* __restrict__ idxoff) {
  int p = blockIdx.x * 256 + threadIdx.x;
  if (p < NPIX) idxoff[p] = img[p] << 7;
}

// Each block: one 32-d chunk x one ROWS-row strip, all 32 images.
// 256 threads = 8 d-subgroups (4 d each, float4) x 32 image slots.
// 32 KB LDS tile -> 4-5 blocks/CU co-resident -> 16-20 waves/CU
// (round-3 showed a 512-thr/64KB block only got 1 block/CU = 8 waves).
template<int ROWS>
__global__ __launch_bounds__(256, 4)
void encode_kernel(const float* __restrict__ V, const float* __restrict__ X,
                   const float* __restrict__ Y, const int* __restrict__ idxoff,
                   float* __restrict__ part) {
  __shared__ float4 vlds[NLEV * 8];    // 32 KB: [level][8 x float4 = 32 d]
  const int tid   = threadIdx.x;
  const int chunk = blockIdx.x;
  const int q     = blockIdx.y;

  // ---- stage V tile: 256 levels x this block's 32 d's ----
  {
    const int seg = tid & 7;           // 16B segment within the 128B tile row
    const int l0  = tid >> 3;          // 0..31
    int off = chunk * TROW + seg * 16; // byte offset into a V row
    if (off + 16 > ROWB) off = ROWB - 16;   // clamp for partial last chunk (values unused)
    const char* Vb = (const char*)V;
#pragma unroll
    for (int k = 0; k < 8; ++k) {
      const int l = k * 32 + l0;
      vlds[l * 8 + seg] = *(const float4*)(Vb + (size_t)l * ROWB + off);
    }
  }
  __syncthreads();

  const int dsub = tid & 7;
  const int b    = tid >> 3;           // image slot 0..31
  const char* vbase = (const char*)vlds + dsub * 16;
  const int d4  = chunk * 32 + dsub * 4;
  const int d4c = d4 > (D_TOT - 4) ? (D_TOT - 4) : d4;   // clamped for x/y loads (lanes past D discarded)
  const int ybase = q * ROWS;

  float4 rowacc[ROWS];
#pragma unroll
  for (int y = 0; y < ROWS; ++y) rowacc[y] = make_float4(0.f, 0.f, 0.f, 0.f);
  const int* iptr = idxoff + b * 4096 + ybase * 64;

#pragma unroll 1
  for (int wt = 0; wt < 8; ++wt) {
    // hoist x fragments for this 8-wide w tile (registers, reused over ROWS rows)
    float4 xt[8];
#pragma unroll
    for (int w = 0; w < 8; ++w)
      xt[w] = *(const float4*)(X + (size_t)(wt * 8 + w) * D_TOT + d4c);
#pragma unroll
    for (int y = 0; y < ROWS; ++y) {
      const int* ip = iptr + y * 64 + wt * 8;
      const int4 o0 = *(const int4*)ip;
      const int4 o1 = *(const int4*)(ip + 4);
      float4 v;
      v = *(const float4*)(vbase + o0.x); rowacc[y] = fma4(xt[0], v, rowacc[y]);
      v = *(const float4*)(vbase + o0.y); rowacc[y] = fma4(xt[1], v, rowacc[y]);
      v = *(const float4*)(vbase + o0.z); rowacc[y] = fma4(xt[2], v, rowacc[y]);
      v = *(const float4*)(vbase + o0.w); rowacc[y] = fma4(xt[3], v, rowacc[y]);
      v = *(const float4*)(vbase + o1.x); rowacc[y] = fma4(xt[4], v, rowacc[y]);
      v = *(const float4*)(vbase + o1.y); rowacc[y] = fma4(xt[5], v, rowacc[y]);
      v = *(const float4*)(vbase + o1.z); rowacc[y] = fma4(xt[6], v, rowacc[y]);
      v = *(const float4*)(vbase + o1.w); rowacc[y] = fma4(xt[7], v, rowacc[y]);
    }
  }

  // apply y binding in ascending row order, then store partial for this strip
  float4 acc = make_float4(0.f, 0.f, 0.f, 0.f);
#pragma unroll
  for (int y = 0; y < ROWS; ++y) {
    const float4 yv = *(const float4*)(Y + (size_t)(ybase + y) * D_TOT + d4c);
    acc = fma4(yv, rowacc[y], acc);
  }
  *(float4*)(part + (size_t)(q * 32 + b) * DPAD + d4) = acc;
}

__global__ void finalize_kernel(const float* __restrict__ part, float* __restrict__ out, int R) {
  const int d = blockIdx.x * 256 + threadIdx.x;
  const int b = blockIdx.y;
  if (d >= D_TOT) return;
  float s = 0.f;
  for (int r = 0; r < R; ++r) s += part[(size_t)(r * 32 + b) * DPAD + d];
  out[(size_t)b * D_TOT + d] = s > 0.f ? 1.0f : -1.0f;
}

extern "C" void kernel_launch(void* const* d_in, const int* in_sizes, int n_in,
                              void* d_out, int out_size, void* d_ws, size_t ws_size,
                              hipStream_t stream) {
  const float* V = (const float*)d_in[0];   // [256][10000]
  const float* X = (const float*)d_in[1];   // [64][10000]
  const float* Y = (const float*)d_in[2];   // [64][10000]
  const int*  img = (const int*)d_in[3];    // [32][1][64][64] levels
  float* out = (float*)d_out;               // [32][10000]

  int* idxoff = (int*)d_ws;
  const size_t base = 524288;               // 131072 * 4
  float* part = (float*)((char*)d_ws + base);

  const size_t per_strip = (size_t)32 * DPAD * 4;
  int R;
  if      (ws_size >= base + 16 * per_strip) R = 16;
  else if (ws_size >= base +  8 * per_strip) R = 8;
  else                                       R = 4;

  prep_kernel<<<dim3(512), dim3(256), 0, stream>>>(img, idxoff);
  if (R == 16)
    encode_kernel<4><<<dim3(NCHUNK, 16), dim3(256), 0, stream>>>(V, X, Y, idxoff, part);
  else if (R == 8)
    encode_kernel<8><<<dim3(NCHUNK, 8), dim3(256), 0, stream>>>(V, X, Y, idxoff, part);
  else
    encode_kernel<16><<<dim3(NCHUNK, 4), dim3(256), 0, stream>>>(V, X, Y, idxoff, part);
  finalize_kernel<<<dim3(40, 32), dim3(256), 0, stream>>>(part, out, R);
}